// Round 1
// baseline (295.981 us; speedup 1.0000x reference)
//
#include <hip/hip_runtime.h>

typedef unsigned short u16;
typedef __attribute__((ext_vector_type(8))) short bf16x8;
typedef __attribute__((ext_vector_type(4))) float f32x4;
typedef __attribute__((ext_vector_type(4))) unsigned int u32x4;

#define SEQ 2048
#define HID 1024
#define NHEAD 16
#define HDIM 64
#define MTOK 4096  // B*S

#define MFMA16(a,b,c) __builtin_amdgcn_mfma_f32_16x16x32_bf16(a,b,c,0,0,0)

__device__ __forceinline__ u16 f2bf(float f){
  unsigned int u = __builtin_bit_cast(unsigned int, f);
  u += 0x7fffu + ((u >> 16) & 1u);
  return (u16)(u >> 16);
}

__device__ __forceinline__ void gload16(const u16* g, u16* l){
  __builtin_amdgcn_global_load_lds((const __attribute__((address_space(1))) void*)g,
                                   (__attribute__((address_space(3))) void*)l, 16, 0, 0);
}

// ---------------- cast fp32 -> bf16, 8 elems/thread ----------------
__global__ __launch_bounds__(256) void cast_f32_bf16(const float* __restrict__ in,
                                                     u16* __restrict__ out, int n8){
  int i = blockIdx.x * 256 + threadIdx.x;
  if (i >= n8) return;
  const float4* p = (const float4*)in;
  float4 a = p[2*i], b = p[2*i+1];
  u32x4 o;
  o.x = (unsigned)f2bf(a.x) | ((unsigned)f2bf(a.y) << 16);
  o.y = (unsigned)f2bf(a.z) | ((unsigned)f2bf(a.w) << 16);
  o.z = (unsigned)f2bf(b.x) | ((unsigned)f2bf(b.y) << 16);
  o.w = (unsigned)f2bf(b.z) | ((unsigned)f2bf(b.w) << 16);
  ((u32x4*)out)[i] = o;
}

// ---------------- fused QKV GEMM: C = X @ Wqkv^T + bias ----------------
// X: [4096][1024] bf16, Wqkv: [3072][1024] bf16 (rows 0-1023=Wq, 1024-2047=Wk, 2048-3071=Wv)
// Writes Q (scaled 1/8), K as [b][h][s][d]; V transposed as [b][h][d][s].
__global__ __launch_bounds__(256) void gemm_qkv(
    const u16* __restrict__ Xb, const u16* __restrict__ Wqkv,
    const float* __restrict__ bq, const float* __restrict__ bk, const float* __restrict__ bv,
    u16* __restrict__ Qb, u16* __restrict__ Kb, u16* __restrict__ Vtb)
{
  __shared__ __attribute__((aligned(16))) u16 As[128*32];
  __shared__ __attribute__((aligned(16))) u16 Bs[128*32];
  const int tid = threadIdx.x, wave = tid >> 6, lane = tid & 63;
  const int m0 = blockIdx.x * 128, n0 = blockIdx.y * 128;
  const int wr = (wave >> 1) * 64, wc = (wave & 1) * 64;
  const int lr = lane & 15, lg = lane >> 4, kseg = lg * 8;
  const int K = HID;

  f32x4 zero = {0.f, 0.f, 0.f, 0.f};
  f32x4 acc[4][4];
#pragma unroll
  for (int i = 0; i < 4; i++)
#pragma unroll
    for (int j = 0; j < 4; j++) acc[i][j] = zero;

  for (int k0 = 0; k0 < K; k0 += 32){
    __syncthreads();
#pragma unroll
    for (int i = 0; i < 2; i++){
      int u = (i*4 + wave) * 64 + lane;
      int row = u >> 2, cu = u & 3;
      gload16(Xb   + (size_t)(m0 + row) * K + k0 + cu*8, As + (i*4 + wave) * 512);
      gload16(Wqkv + (size_t)(n0 + row) * K + k0 + cu*8, Bs + (i*4 + wave) * 512);
    }
    __syncthreads();
    bf16x8 af[4], bfr[4];
#pragma unroll
    for (int m = 0; m < 4; m++) af[m]  = *(const bf16x8*)&As[(wr + m*16 + lr)*32 + kseg];
#pragma unroll
    for (int n = 0; n < 4; n++) bfr[n] = *(const bf16x8*)&Bs[(wc + n*16 + lr)*32 + kseg];
#pragma unroll
    for (int m = 0; m < 4; m++)
#pragma unroll
      for (int n = 0; n < 4; n++)
        acc[m][n] = MFMA16(af[m], bfr[n], acc[m][n]);
  }

  const int sel = n0 >> 10;                       // 0=q 1=k 2=v (tiles never straddle)
  const float* bias = (sel == 0) ? bq : (sel == 1) ? bk : bv;
  const float qscale = (sel == 0) ? 0.125f : 1.0f;
#pragma unroll
  for (int n = 0; n < 4; n++){
    int col = n0 + wc + n*16 + lr;
    int o = col & 1023;
    float bb = bias[o];
    int h = o >> 6, d = o & 63;
#pragma unroll
    for (int m = 0; m < 4; m++){
      int rbase = m0 + wr + m*16 + lg*4;
#pragma unroll
      for (int r = 0; r < 4; r++){
        int rowg = rbase + r;
        int b = rowg >> 11, s = rowg & 2047;
        u16 v = f2bf((acc[m][n][r] + bb) * qscale);
        if (sel == 0)      Qb [(((size_t)(b*16 + h))*SEQ + s)*HDIM + d] = v;
        else if (sel == 1) Kb [(((size_t)(b*16 + h))*SEQ + s)*HDIM + d] = v;
        else               Vtb[(((size_t)(b*16 + h))*HDIM + d)*SEQ + s] = v;
      }
    }
  }
}

// ---------------- flash attention ----------------
// grid: x = S/64 q-tiles, y = B*NH. 4 waves x 16 q-rows. KV tiles of 64.
__global__ __launch_bounds__(256) void attn_kernel(
    const u16* __restrict__ Qb, const u16* __restrict__ Kb, const u16* __restrict__ Vtb,
    u16* __restrict__ AOb)
{
  __shared__ __attribute__((aligned(16))) u16 Ks[64*64];
  __shared__ __attribute__((aligned(16))) u16 Vs[64*64];
  __shared__ __attribute__((aligned(16))) u16 Ps[4][16][80];  // per-wave P, padded rows
  const int tid = threadIdx.x, wave = tid >> 6, lane = tid & 63;
  const int lr = lane & 15, lg = lane >> 4, kseg = lg * 8;
  const int bh = blockIdx.y;
  const int q0 = blockIdx.x * 64;
  const u16* Qh = Qb  + (size_t)bh * SEQ * HDIM;
  const u16* Kh = Kb  + (size_t)bh * SEQ * HDIM;
  const u16* Vh = Vtb + (size_t)bh * HDIM * SEQ;

  const int qrow = q0 + wave*16 + lr;
  bf16x8 qf0 = *(const bf16x8*)&Qh[(size_t)qrow * HDIM + kseg];
  bf16x8 qf1 = *(const bf16x8*)&Qh[(size_t)qrow * HDIM + 32 + kseg];

  f32x4 zero = {0.f, 0.f, 0.f, 0.f};
  f32x4 acc_o[4];
#pragma unroll
  for (int fd = 0; fd < 4; fd++) acc_o[fd] = zero;
  float m_r[4] = {-1e30f, -1e30f, -1e30f, -1e30f};
  float l_r[4] = {0.f, 0.f, 0.f, 0.f};

  for (int kv0 = 0; kv0 < SEQ; kv0 += 64){
    __syncthreads();
#pragma unroll
    for (int i = 0; i < 2; i++){
      int u = (i*4 + wave) * 64 + lane;
      gload16(Kh + (size_t)kv0 * 64 + u*8, Ks + (i*4 + wave) * 512);
      int row = u >> 3, cu = u & 7;
      gload16(Vh + (size_t)row * SEQ + kv0 + cu*8, Vs + (i*4 + wave) * 512);
    }
    __syncthreads();

    // S = Q K^T (scale pre-folded into Q)
    f32x4 sf[4];
#pragma unroll
    for (int f = 0; f < 4; f++){
      sf[f] = zero;
      bf16x8 b0 = *(const bf16x8*)&Ks[(f*16 + lr)*64 + kseg];
      bf16x8 b1 = *(const bf16x8*)&Ks[(f*16 + lr)*64 + 32 + kseg];
      sf[f] = MFMA16(qf0, b0, sf[f]);
      sf[f] = MFMA16(qf1, b1, sf[f]);
    }

    // online softmax: rows = lg*4+r, cols across lanes (lr) x 4 frags
    float alpha[4];
#pragma unroll
    for (int r = 0; r < 4; r++){
      float mx = fmaxf(fmaxf(sf[0][r], sf[1][r]), fmaxf(sf[2][r], sf[3][r]));
#pragma unroll
      for (int off = 8; off >= 1; off >>= 1) mx = fmaxf(mx, __shfl_xor(mx, off));
      float mn = fmaxf(m_r[r], mx);
      alpha[r] = __expf(m_r[r] - mn);
      m_r[r] = mn;
    }
#pragma unroll
    for (int r = 0; r < 4; r++){
      float s = 0.f;
#pragma unroll
      for (int f = 0; f < 4; f++){
        float p = __expf(sf[f][r] - m_r[r]);
        sf[f][r] = p;
        s += p;
      }
#pragma unroll
      for (int off = 8; off >= 1; off >>= 1) s += __shfl_xor(s, off);
      l_r[r] = l_r[r] * alpha[r] + s;
    }
    // P -> per-wave LDS (bf16)
#pragma unroll
    for (int f = 0; f < 4; f++)
#pragma unroll
      for (int r = 0; r < 4; r++)
        Ps[wave][lg*4 + r][f*16 + lr] = f2bf(sf[f][r]);
    // rescale O
#pragma unroll
    for (int fd = 0; fd < 4; fd++)
#pragma unroll
      for (int r = 0; r < 4; r++)
        acc_o[fd][r] *= alpha[r];

    // PV: A = P[16 q][64 kv], B = V[kv][d] read from transposed Vs[d][kv]
    bf16x8 p0 = *(const bf16x8*)&Ps[wave][lr][kseg];
    bf16x8 p1 = *(const bf16x8*)&Ps[wave][lr][32 + kseg];
#pragma unroll
    for (int fd = 0; fd < 4; fd++){
      bf16x8 v0 = *(const bf16x8*)&Vs[(fd*16 + lr)*64 + kseg];
      bf16x8 v1 = *(const bf16x8*)&Vs[(fd*16 + lr)*64 + 32 + kseg];
      acc_o[fd] = MFMA16(p0, v0, acc_o[fd]);
      acc_o[fd] = MFMA16(p1, v1, acc_o[fd]);
    }
  }

  // epilogue: AOb[b][s][h*64+d] bf16
  const int b = bh >> 4, h = bh & 15;
#pragma unroll
  for (int fd = 0; fd < 4; fd++){
    int d = h*64 + fd*16 + lr;
#pragma unroll
    for (int r = 0; r < 4; r++){
      int s = q0 + wave*16 + lg*4 + r;
      AOb[((size_t)(b*SEQ + s))*HID + d] = f2bf(acc_o[fd][r] / l_r[r]);
    }
  }
}

// ---------------- output projection: Out = AO @ Wo^T + bo (fp32 out) ----------------
__global__ __launch_bounds__(256) void gemm_out(
    const u16* __restrict__ Ab, const u16* __restrict__ Wob,
    const float* __restrict__ bo, float* __restrict__ Out)
{
  __shared__ __attribute__((aligned(16))) u16 As[128*32];
  __shared__ __attribute__((aligned(16))) u16 Bs[128*32];
  const int tid = threadIdx.x, wave = tid >> 6, lane = tid & 63;
  const int m0 = blockIdx.x * 128, n0 = blockIdx.y * 128;
  const int wr = (wave >> 1) * 64, wc = (wave & 1) * 64;
  const int lr = lane & 15, lg = lane >> 4, kseg = lg * 8;
  const int K = HID;

  f32x4 zero = {0.f, 0.f, 0.f, 0.f};
  f32x4 acc[4][4];
#pragma unroll
  for (int i = 0; i < 4; i++)
#pragma unroll
    for (int j = 0; j < 4; j++) acc[i][j] = zero;

  for (int k0 = 0; k0 < K; k0 += 32){
    __syncthreads();
#pragma unroll
    for (int i = 0; i < 2; i++){
      int u = (i*4 + wave) * 64 + lane;
      int row = u >> 2, cu = u & 3;
      gload16(Ab  + (size_t)(m0 + row) * K + k0 + cu*8, As + (i*4 + wave) * 512);
      gload16(Wob + (size_t)(n0 + row) * K + k0 + cu*8, Bs + (i*4 + wave) * 512);
    }
    __syncthreads();
    bf16x8 af[4], bfr[4];
#pragma unroll
    for (int m = 0; m < 4; m++) af[m]  = *(const bf16x8*)&As[(wr + m*16 + lr)*32 + kseg];
#pragma unroll
    for (int n = 0; n < 4; n++) bfr[n] = *(const bf16x8*)&Bs[(wc + n*16 + lr)*32 + kseg];
#pragma unroll
    for (int m = 0; m < 4; m++)
#pragma unroll
      for (int n = 0; n < 4; n++)
        acc[m][n] = MFMA16(af[m], bfr[n], acc[m][n]);
  }

#pragma unroll
  for (int n = 0; n < 4; n++){
    int col = n0 + wc + n*16 + lr;
    float bb = bo[col];
#pragma unroll
    for (int m = 0; m < 4; m++){
      int rbase = m0 + wr + m*16 + lg*4;
#pragma unroll
      for (int r = 0; r < 4; r++)
        Out[(size_t)(rbase + r) * HID + col] = acc[m][n][r] + bb;
    }
  }
}

extern "C" void kernel_launch(void* const* d_in, const int* in_sizes, int n_in,
                              void* d_out, int out_size, void* d_ws, size_t ws_size,
                              hipStream_t stream){
  const float* hs = (const float*)d_in[0];
  const float* Wq = (const float*)d_in[1];
  const float* bq = (const float*)d_in[2];
  const float* Wk = (const float*)d_in[3];
  const float* bk = (const float*)d_in[4];
  const float* Wv = (const float*)d_in[5];
  const float* bv = (const float*)d_in[6];
  const float* Wo = (const float*)d_in[7];
  const float* bo = (const float*)d_in[8];
  float* Out = (float*)d_out;

  // workspace carve (48 MB total, all 16B-aligned)
  u16* Xb   = (u16*)d_ws;                          // 4096x1024
  u16* Wqkv = Xb   + (size_t)MTOK * HID;           // 3072x1024
  u16* Wob  = Wqkv + (size_t)3 * HID * HID;        // 1024x1024
  u16* Qb   = Wob  + (size_t)HID * HID;            // [b][h][s][d]
  u16* Kb   = Qb   + (size_t)MTOK * HID;           // [b][h][s][d]
  u16* Vtb  = Kb   + (size_t)MTOK * HID;           // [b][h][d][s]
  u16* AOb  = Vtb  + (size_t)MTOK * HID;           // [b][s][h*d]

  cast_f32_bf16<<<2048, 256, 0, stream>>>(hs, Xb, MTOK * HID / 8);
  cast_f32_bf16<<<512, 256, 0, stream>>>(Wq, Wqkv,                 HID * HID / 8);
  cast_f32_bf16<<<512, 256, 0, stream>>>(Wk, Wqkv + HID*HID,       HID * HID / 8);
  cast_f32_bf16<<<512, 256, 0, stream>>>(Wv, Wqkv + 2*HID*HID,     HID * HID / 8);
  cast_f32_bf16<<<512, 256, 0, stream>>>(Wo, Wob,                  HID * HID / 8);

  gemm_qkv<<<dim3(MTOK/128, 3*HID/128), 256, 0, stream>>>(Xb, Wqkv, bq, bk, bv, Qb, Kb, Vtb);
  attn_kernel<<<dim3(SEQ/64, 2*NHEAD), 256, 0, stream>>>(Qb, Kb, Vtb, AOb);
  gemm_out<<<dim3(MTOK/128, HID/128), 256, 0, stream>>>(AOb, Wob, bo, Out);
}

// Round 2
// 220.055 us; speedup vs baseline: 1.3450x; 1.3450x over previous
//
#include <hip/hip_runtime.h>

typedef unsigned short u16;
typedef __attribute__((ext_vector_type(8))) short bf16x8;
typedef __attribute__((ext_vector_type(4))) float f32x4;
typedef __attribute__((ext_vector_type(4))) unsigned int u32x4;

#define SEQ 2048
#define HID 1024
#define NHEAD 16
#define HDIM 64
#define MTOK 4096  // B*S

#define MFMA16(a,b,c) __builtin_amdgcn_mfma_f32_16x16x32_bf16(a,b,c,0,0,0)

__device__ __forceinline__ u16 f2bf(float f){
  unsigned int u = __builtin_bit_cast(unsigned int, f);
  u += 0x7fffu + ((u >> 16) & 1u);
  return (u16)(u >> 16);
}

__device__ __forceinline__ void gload16(const u16* g, u16* l){
  __builtin_amdgcn_global_load_lds((const __attribute__((address_space(1))) void*)g,
                                   (__attribute__((address_space(3))) void*)l, 16, 0, 0);
}

// ---------------- cast fp32 -> bf16, 8 elems/thread ----------------
__global__ __launch_bounds__(256) void cast_f32_bf16(const float* __restrict__ in,
                                                     u16* __restrict__ out, int n8){
  int i = blockIdx.x * 256 + threadIdx.x;
  if (i >= n8) return;
  const float4* p = (const float4*)in;
  float4 a = p[2*i], b = p[2*i+1];
  u32x4 o;
  o.x = (unsigned)f2bf(a.x) | ((unsigned)f2bf(a.y) << 16);
  o.y = (unsigned)f2bf(a.z) | ((unsigned)f2bf(a.w) << 16);
  o.z = (unsigned)f2bf(b.x) | ((unsigned)f2bf(b.y) << 16);
  o.w = (unsigned)f2bf(b.z) | ((unsigned)f2bf(b.w) << 16);
  ((u32x4*)out)[i] = o;
}

// all four 1024x1024 weight casts in one launch (y = which)
__global__ __launch_bounds__(256) void cast_w4(const float* __restrict__ Wq,
                                               const float* __restrict__ Wk,
                                               const float* __restrict__ Wv,
                                               const float* __restrict__ Wo,
                                               u16* __restrict__ Wqkv, u16* __restrict__ Wob){
  int which = blockIdx.y;
  const float* src = (which == 0) ? Wq : (which == 1) ? Wk : (which == 2) ? Wv : Wo;
  u16* dst = (which == 3) ? Wob : (Wqkv + (size_t)which * HID * HID);
  int i = blockIdx.x * 256 + threadIdx.x;
  const float4* p = (const float4*)src;
  float4 a = p[2*i], b = p[2*i+1];
  u32x4 o;
  o.x = (unsigned)f2bf(a.x) | ((unsigned)f2bf(a.y) << 16);
  o.y = (unsigned)f2bf(a.z) | ((unsigned)f2bf(a.w) << 16);
  o.z = (unsigned)f2bf(b.x) | ((unsigned)f2bf(b.y) << 16);
  o.w = (unsigned)f2bf(b.z) | ((unsigned)f2bf(b.w) << 16);
  ((u32x4*)dst)[i] = o;
}

// ---------------- fused QKV GEMM: C = X @ Wqkv^T + bias ----------------
__global__ __launch_bounds__(256) void gemm_qkv(
    const u16* __restrict__ Xb, const u16* __restrict__ Wqkv,
    const float* __restrict__ bq, const float* __restrict__ bk, const float* __restrict__ bv,
    u16* __restrict__ Qb, u16* __restrict__ Kb, u16* __restrict__ Vtb)
{
  __shared__ __attribute__((aligned(16))) u16 As[128*32];
  __shared__ __attribute__((aligned(16))) u16 Bs[128*32];
  const int tid = threadIdx.x, wave = tid >> 6, lane = tid & 63;
  const int m0 = blockIdx.x * 128, n0 = blockIdx.y * 128;
  const int wr = (wave >> 1) * 64, wc = (wave & 1) * 64;
  const int lr = lane & 15, lg = lane >> 4, kseg = lg * 8;
  const int K = HID;

  f32x4 zero = {0.f, 0.f, 0.f, 0.f};
  f32x4 acc[4][4];
#pragma unroll
  for (int i = 0; i < 4; i++)
#pragma unroll
    for (int j = 0; j < 4; j++) acc[i][j] = zero;

  for (int k0 = 0; k0 < K; k0 += 32){
    __syncthreads();
#pragma unroll
    for (int i = 0; i < 2; i++){
      int u = (i*4 + wave) * 64 + lane;
      int row = u >> 2, cu = u & 3;
      gload16(Xb   + (size_t)(m0 + row) * K + k0 + cu*8, As + (i*4 + wave) * 512);
      gload16(Wqkv + (size_t)(n0 + row) * K + k0 + cu*8, Bs + (i*4 + wave) * 512);
    }
    __syncthreads();
    bf16x8 af[4], bfr[4];
#pragma unroll
    for (int m = 0; m < 4; m++) af[m]  = *(const bf16x8*)&As[(wr + m*16 + lr)*32 + kseg];
#pragma unroll
    for (int n = 0; n < 4; n++) bfr[n] = *(const bf16x8*)&Bs[(wc + n*16 + lr)*32 + kseg];
#pragma unroll
    for (int m = 0; m < 4; m++)
#pragma unroll
      for (int n = 0; n < 4; n++)
        acc[m][n] = MFMA16(af[m], bfr[n], acc[m][n]);
  }

  const int sel = n0 >> 10;                       // 0=q 1=k 2=v (tiles never straddle)
  const float* bias = (sel == 0) ? bq : (sel == 1) ? bk : bv;
  const float qscale = (sel == 0) ? 0.125f : 1.0f;
#pragma unroll
  for (int n = 0; n < 4; n++){
    int col = n0 + wc + n*16 + lr;
    int o = col & 1023;
    float bb = bias[o];
    int h = o >> 6, d = o & 63;
#pragma unroll
    for (int m = 0; m < 4; m++){
      int rbase = m0 + wr + m*16 + lg*4;
#pragma unroll
      for (int r = 0; r < 4; r++){
        int rowg = rbase + r;
        int b = rowg >> 11, s = rowg & 2047;
        u16 v = f2bf((acc[m][n][r] + bb) * qscale);
        if (sel == 0)      Qb [(((size_t)(b*16 + h))*SEQ + s)*HDIM + d] = v;
        else if (sel == 1) Kb [(((size_t)(b*16 + h))*SEQ + s)*HDIM + d] = v;
        else               Vtb[(((size_t)(b*16 + h))*HDIM + d)*SEQ + s] = v;
      }
    }
  }
}

// ---------------- flash attention (swapped QK^T, swizzled LDS, defer-max) ----------------
// grid: x = S/128 q-tiles, y = B*NH. 4 waves x 32 q-rows. KV tiles of 64.
// K/V LDS tiles: row = 64 bf16 = 8 slots of 16B; slot' = slot ^ (row&7) (involution,
// applied on the *global source* of global_load_lds and again on the read side).
__global__ __launch_bounds__(256) void attn_kernel(
    const u16* __restrict__ Qb, const u16* __restrict__ Kb, const u16* __restrict__ Vtb,
    u16* __restrict__ AOb)
{
  __shared__ __attribute__((aligned(16))) u16 Ks[64*64];     // [kv][d] swizzled
  __shared__ __attribute__((aligned(16))) u16 Vs[64*64];     // [d][kv] swizzled
  __shared__ __attribute__((aligned(16))) u16 Ps[4][32][72]; // per-wave P[q][kv], pad 72
  const int tid = threadIdx.x, wave = tid >> 6, lane = tid & 63;
  const int lr = lane & 15, lg = lane >> 4;
  const int bh = blockIdx.y;
  const int q0 = blockIdx.x * 128;
  const u16* Qh = Qb  + (size_t)bh * SEQ * HDIM;
  const u16* Kh = Kb  + (size_t)bh * SEQ * HDIM;
  const u16* Vh = Vtb + (size_t)bh * HDIM * SEQ;

  // Q B-frags (col=q=lr, k=d): qf[qb][ks]
  bf16x8 qf[2][2];
#pragma unroll
  for (int qb = 0; qb < 2; qb++)
#pragma unroll
    for (int ks = 0; ks < 2; ks++)
      qf[qb][ks] = *(const bf16x8*)&Qh[(size_t)(q0 + wave*32 + qb*16 + lr) * HDIM + ks*32 + lg*8];

  f32x4 zero = {0.f, 0.f, 0.f, 0.f};
  f32x4 acc[2][4];
#pragma unroll
  for (int qb = 0; qb < 2; qb++)
#pragma unroll
    for (int fd = 0; fd < 4; fd++) acc[qb][fd] = zero;
  float m_c[2] = {-1e30f, -1e30f};
  float l_c[2] = {0.f, 0.f};

  for (int kv0 = 0; kv0 < SEQ; kv0 += 64){
    __syncthreads();
#pragma unroll
    for (int i = 0; i < 2; i++){
      int u = i*256 + tid;
      int r = u >> 3, s = u & 7, ss = s ^ (r & 7);
      gload16(Kh + (size_t)(kv0 + r) * HDIM + ss*8, Ks + u*8);
      gload16(Vh + (size_t)r * SEQ + kv0 + ss*8,    Vs + u*8);
    }
    __syncthreads();

    // S^T = K Q^T: col=lr=q, row=lg*4+r=kv within block f
    f32x4 st[2][4];
    __builtin_amdgcn_s_setprio(1);
#pragma unroll
    for (int f = 0; f < 4; f++){
      bf16x8 kf0 = *(const bf16x8*)&Ks[(f*16 + lr)*64 + ((lg     ^ (lr & 7)) * 8)];
      bf16x8 kf1 = *(const bf16x8*)&Ks[(f*16 + lr)*64 + (((4+lg) ^ (lr & 7)) * 8)];
      st[0][f] = MFMA16(kf0, qf[0][0], zero);
      st[0][f] = MFMA16(kf1, qf[0][1], st[0][f]);
      st[1][f] = MFMA16(kf0, qf[1][0], zero);
      st[1][f] = MFMA16(kf1, qf[1][1], st[1][f]);
    }
    __builtin_amdgcn_s_setprio(0);

    // per-lane online softmax for q = qb*16 + lr (16 kv values in-lane, rest in lanes lr+16k)
    float mtv[2];
#pragma unroll
    for (int qb = 0; qb < 2; qb++){
      float mt = st[qb][0][0];
#pragma unroll
      for (int f = 0; f < 4; f++)
#pragma unroll
        for (int r = 0; r < 4; r++) mt = fmaxf(mt, st[qb][f][r]);
      mt = fmaxf(mt, __shfl_xor(mt, 16));
      mt = fmaxf(mt, __shfl_xor(mt, 32));
      mtv[qb] = mt;
    }
    int need = (mtv[0] > m_c[0] + 8.f) || (mtv[1] > m_c[1] + 8.f);
    if (__any(need)){
#pragma unroll
      for (int qb = 0; qb < 2; qb++){
        float mn = fmaxf(m_c[qb], mtv[qb]);
        float al = __expf(m_c[qb] - mn);
        m_c[qb] = mn;
        l_c[qb] *= al;
        float a[4];
#pragma unroll
        for (int r = 0; r < 4; r++) a[r] = __shfl(al, lg*4 + r);
#pragma unroll
        for (int fd = 0; fd < 4; fd++)
#pragma unroll
          for (int r = 0; r < 4; r++) acc[qb][fd][r] *= a[r];
      }
    }
#pragma unroll
    for (int qb = 0; qb < 2; qb++){
      float s_t = 0.f;
#pragma unroll
      for (int f = 0; f < 4; f++){
        float p0 = __expf(st[qb][f][0] - m_c[qb]);
        float p1 = __expf(st[qb][f][1] - m_c[qb]);
        float p2 = __expf(st[qb][f][2] - m_c[qb]);
        float p3 = __expf(st[qb][f][3] - m_c[qb]);
        s_t += (p0 + p1) + (p2 + p3);
        unsigned w0 = (unsigned)f2bf(p0) | ((unsigned)f2bf(p1) << 16);
        unsigned w1 = (unsigned)f2bf(p2) | ((unsigned)f2bf(p3) << 16);
        *(uint2*)&Ps[wave][qb*16 + lr][f*16 + lg*4] = make_uint2(w0, w1);
      }
      s_t += __shfl_xor(s_t, 16);
      s_t += __shfl_xor(s_t, 32);
      l_c[qb] += s_t;
    }

    // PV: A=P[q][kv], B=V^T[d][kv] -> acc[q][d]
    __builtin_amdgcn_s_setprio(1);
#pragma unroll
    for (int ks = 0; ks < 2; ks++){
      bf16x8 pf0 = *(const bf16x8*)&Ps[wave][lr]     [ks*32 + lg*8];
      bf16x8 pf1 = *(const bf16x8*)&Ps[wave][16 + lr][ks*32 + lg*8];
#pragma unroll
      for (int fd = 0; fd < 4; fd++){
        bf16x8 vf = *(const bf16x8*)&Vs[(fd*16 + lr)*64 + (((ks*4 + lg) ^ (lr & 7)) * 8)];
        acc[0][fd] = MFMA16(pf0, vf, acc[0][fd]);
        acc[1][fd] = MFMA16(pf1, vf, acc[1][fd]);
      }
    }
    __builtin_amdgcn_s_setprio(0);
  }

  // epilogue: transpose l to acc layout once; AOb[b][s][h*64+d] bf16
  const int b = bh >> 4, h = bh & 15;
#pragma unroll
  for (int qb = 0; qb < 2; qb++){
    float li[4];
#pragma unroll
    for (int r = 0; r < 4; r++) li[r] = 1.0f / __shfl(l_c[qb], lg*4 + r);
#pragma unroll
    for (int fd = 0; fd < 4; fd++){
      int d = h*64 + fd*16 + lr;
#pragma unroll
      for (int r = 0; r < 4; r++){
        int s = q0 + wave*32 + qb*16 + lg*4 + r;
        AOb[((size_t)(b*SEQ + s))*HID + d] = f2bf(acc[qb][fd][r] * li[r]);
      }
    }
  }
}

// ---------------- output projection: Out = AO @ Wo^T + bo (fp32 out) ----------------
__global__ __launch_bounds__(256) void gemm_out(
    const u16* __restrict__ Ab, const u16* __restrict__ Wob,
    const float* __restrict__ bo, float* __restrict__ Out)
{
  __shared__ __attribute__((aligned(16))) u16 As[128*32];
  __shared__ __attribute__((aligned(16))) u16 Bs[128*32];
  const int tid = threadIdx.x, wave = tid >> 6, lane = tid & 63;
  const int m0 = blockIdx.x * 128, n0 = blockIdx.y * 128;
  const int wr = (wave >> 1) * 64, wc = (wave & 1) * 64;
  const int lr = lane & 15, lg = lane >> 4, kseg = lg * 8;
  const int K = HID;

  f32x4 zero = {0.f, 0.f, 0.f, 0.f};
  f32x4 acc[4][4];
#pragma unroll
  for (int i = 0; i < 4; i++)
#pragma unroll
    for (int j = 0; j < 4; j++) acc[i][j] = zero;

  for (int k0 = 0; k0 < K; k0 += 32){
    __syncthreads();
#pragma unroll
    for (int i = 0; i < 2; i++){
      int u = (i*4 + wave) * 64 + lane;
      int row = u >> 2, cu = u & 3;
      gload16(Ab  + (size_t)(m0 + row) * K + k0 + cu*8, As + (i*4 + wave) * 512);
      gload16(Wob + (size_t)(n0 + row) * K + k0 + cu*8, Bs + (i*4 + wave) * 512);
    }
    __syncthreads();
    bf16x8 af[4], bfr[4];
#pragma unroll
    for (int m = 0; m < 4; m++) af[m]  = *(const bf16x8*)&As[(wr + m*16 + lr)*32 + kseg];
#pragma unroll
    for (int n = 0; n < 4; n++) bfr[n] = *(const bf16x8*)&Bs[(wc + n*16 + lr)*32 + kseg];
#pragma unroll
    for (int m = 0; m < 4; m++)
#pragma unroll
      for (int n = 0; n < 4; n++)
        acc[m][n] = MFMA16(af[m], bfr[n], acc[m][n]);
  }

#pragma unroll
  for (int n = 0; n < 4; n++){
    int col = n0 + wc + n*16 + lr;
    float bb = bo[col];
#pragma unroll
    for (int m = 0; m < 4; m++){
      int rbase = m0 + wr + m*16 + lg*4;
#pragma unroll
      for (int r = 0; r < 4; r++)
        Out[(size_t)(rbase + r) * HID + col] = acc[m][n][r] + bb;
    }
  }
}

extern "C" void kernel_launch(void* const* d_in, const int* in_sizes, int n_in,
                              void* d_out, int out_size, void* d_ws, size_t ws_size,
                              hipStream_t stream){
  const float* hs = (const float*)d_in[0];
  const float* Wq = (const float*)d_in[1];
  const float* bq = (const float*)d_in[2];
  const float* Wk = (const float*)d_in[3];
  const float* bk = (const float*)d_in[4];
  const float* Wv = (const float*)d_in[5];
  const float* bv = (const float*)d_in[6];
  const float* Wo = (const float*)d_in[7];
  const float* bo = (const float*)d_in[8];
  float* Out = (float*)d_out;

  u16* Xb   = (u16*)d_ws;                          // 4096x1024
  u16* Wqkv = Xb   + (size_t)MTOK * HID;           // 3072x1024
  u16* Wob  = Wqkv + (size_t)3 * HID * HID;        // 1024x1024
  u16* Qb   = Wob  + (size_t)HID * HID;            // [b][h][s][d]
  u16* Kb   = Qb   + (size_t)MTOK * HID;           // [b][h][s][d]
  u16* Vtb  = Kb   + (size_t)MTOK * HID;           // [b][h][d][s]
  u16* AOb  = Vtb  + (size_t)MTOK * HID;           // [b][s][h*d]

  cast_f32_bf16<<<2048, 256, 0, stream>>>(hs, Xb, MTOK * HID / 8);
  cast_w4<<<dim3(HID*HID/8/256, 4), 256, 0, stream>>>(Wq, Wk, Wv, Wo, Wqkv, Wob);

  gemm_qkv<<<dim3(MTOK/128, 3*HID/128), 256, 0, stream>>>(Xb, Wqkv, bq, bk, bv, Qb, Kb, Vtb);
  attn_kernel<<<dim3(SEQ/128, 2*NHEAD), 256, 0, stream>>>(Qb, Kb, Vtb, AOb);
  gemm_out<<<dim3(MTOK/128, HID/128), 256, 0, stream>>>(AOb, Wob, bo, Out);
}

// Round 3
// 208.899 us; speedup vs baseline: 1.4169x; 1.0534x over previous
//
#include <hip/hip_runtime.h>

typedef unsigned short u16;
typedef __attribute__((ext_vector_type(8))) short bf16x8;
typedef __attribute__((ext_vector_type(4))) float f32x4;
typedef __attribute__((ext_vector_type(4))) unsigned int u32x4;

#define SEQ 2048
#define HID 1024
#define NHEAD 16
#define HDIM 64
#define MTOK 4096  // B*S

#define MFMA16(a,b,c) __builtin_amdgcn_mfma_f32_16x16x32_bf16(a,b,c,0,0,0)

__device__ __forceinline__ u16 f2bf(float f){
  unsigned int u = __builtin_bit_cast(unsigned int, f);
  u += 0x7fffu + ((u >> 16) & 1u);
  return (u16)(u >> 16);
}

__device__ __forceinline__ void gload16(const u16* g, u16* l){
  __builtin_amdgcn_global_load_lds((const __attribute__((address_space(1))) void*)g,
                                   (__attribute__((address_space(3))) void*)l, 16, 0, 0);
}

// ---------------- cast fp32 -> bf16, 8 elems/thread ----------------
__global__ __launch_bounds__(256) void cast_f32_bf16(const float* __restrict__ in,
                                                     u16* __restrict__ out, int n8){
  int i = blockIdx.x * 256 + threadIdx.x;
  if (i >= n8) return;
  const float4* p = (const float4*)in;
  float4 a = p[2*i], b = p[2*i+1];
  u32x4 o;
  o.x = (unsigned)f2bf(a.x) | ((unsigned)f2bf(a.y) << 16);
  o.y = (unsigned)f2bf(a.z) | ((unsigned)f2bf(a.w) << 16);
  o.z = (unsigned)f2bf(b.x) | ((unsigned)f2bf(b.y) << 16);
  o.w = (unsigned)f2bf(b.z) | ((unsigned)f2bf(b.w) << 16);
  ((u32x4*)out)[i] = o;
}

// all four 1024x1024 weight casts in one launch (y = which)
__global__ __launch_bounds__(256) void cast_w4(const float* __restrict__ Wq,
                                               const float* __restrict__ Wk,
                                               const float* __restrict__ Wv,
                                               const float* __restrict__ Wo,
                                               u16* __restrict__ Wqkv, u16* __restrict__ Wob){
  int which = blockIdx.y;
  const float* src = (which == 0) ? Wq : (which == 1) ? Wk : (which == 2) ? Wv : Wo;
  u16* dst = (which == 3) ? Wob : (Wqkv + (size_t)which * HID * HID);
  int i = blockIdx.x * 256 + threadIdx.x;
  const float4* p = (const float4*)src;
  float4 a = p[2*i], b = p[2*i+1];
  u32x4 o;
  o.x = (unsigned)f2bf(a.x) | ((unsigned)f2bf(a.y) << 16);
  o.y = (unsigned)f2bf(a.z) | ((unsigned)f2bf(a.w) << 16);
  o.z = (unsigned)f2bf(b.x) | ((unsigned)f2bf(b.y) << 16);
  o.w = (unsigned)f2bf(b.z) | ((unsigned)f2bf(b.w) << 16);
  ((u32x4*)dst)[i] = o;
}

// GEMM staging: double-buffered, single-barrier loop (raw s_barrier + counted vmcnt)
#define STAGE_G(Ag, Bg, k0, buf) do { \
  _Pragma("unroll") \
  for (int i_ = 0; i_ < 2; i_++){ \
    int u_ = (i_*4 + wave) * 64 + lane; \
    int row_ = u_ >> 2, cu_ = u_ & 3; \
    gload16(Ag + (size_t)(m0 + row_) * HID + (k0) + cu_*8, &As[buf][(i_*4 + wave) * 512]); \
    gload16(Bg + (size_t)(n0 + row_) * HID + (k0) + cu_*8, &Bs[buf][(i_*4 + wave) * 512]); \
  } } while(0)

// ---------------- fused QKV GEMM: C = X @ Wqkv^T + bias ----------------
__global__ __launch_bounds__(256) void gemm_qkv(
    const u16* __restrict__ Xb, const u16* __restrict__ Wqkv,
    const float* __restrict__ bq, const float* __restrict__ bk, const float* __restrict__ bv,
    u16* __restrict__ Qb, u16* __restrict__ Kb, u16* __restrict__ Vtb)
{
  __shared__ __attribute__((aligned(16))) u16 As[2][128*32];
  __shared__ __attribute__((aligned(16))) u16 Bs[2][128*32];
  const int tid = threadIdx.x, wave = tid >> 6, lane = tid & 63;
  const int m0 = blockIdx.x * 128, n0 = blockIdx.y * 128;
  const int wr = (wave >> 1) * 64, wc = (wave & 1) * 64;
  const int lr = lane & 15, lg = lane >> 4, kseg = lg * 8;

  f32x4 zero = {0.f, 0.f, 0.f, 0.f};
  f32x4 acc[4][4];
#pragma unroll
  for (int i = 0; i < 4; i++)
#pragma unroll
    for (int j = 0; j < 4; j++) acc[i][j] = zero;

  STAGE_G(Xb, Wqkv, 0, 0);
  for (int t = 0; t < 32; t++){
    int cur = t & 1;
    asm volatile("s_waitcnt vmcnt(0)" ::: "memory");
    __builtin_amdgcn_s_barrier();
    __builtin_amdgcn_sched_barrier(0);
    if (t < 31) STAGE_G(Xb, Wqkv, (t+1)*32, cur ^ 1);
    const u16* Ac = As[cur]; const u16* Bc = Bs[cur];
    bf16x8 af[4], bfr[4];
#pragma unroll
    for (int m = 0; m < 4; m++) af[m]  = *(const bf16x8*)&Ac[(wr + m*16 + lr)*32 + kseg];
#pragma unroll
    for (int n = 0; n < 4; n++) bfr[n] = *(const bf16x8*)&Bc[(wc + n*16 + lr)*32 + kseg];
    __builtin_amdgcn_s_setprio(1);
#pragma unroll
    for (int m = 0; m < 4; m++)
#pragma unroll
      for (int n = 0; n < 4; n++)
        acc[m][n] = MFMA16(af[m], bfr[n], acc[m][n]);
    __builtin_amdgcn_s_setprio(0);
  }

  const int sel = n0 >> 10;                       // 0=q 1=k 2=v (tiles never straddle)
  const float* bias = (sel == 0) ? bq : (sel == 1) ? bk : bv;
  // q pre-scaled by 1/sqrt(d) * log2(e) so attention works in exp2 domain
  const float qscale = (sel == 0) ? 0.18033688011f : 1.0f;
#pragma unroll
  for (int n = 0; n < 4; n++){
    int col = n0 + wc + n*16 + lr;
    int o = col & 1023;
    float bb = bias[o];
    int h = o >> 6, d = o & 63;
#pragma unroll
    for (int m = 0; m < 4; m++){
      int rbase = m0 + wr + m*16 + lg*4;
#pragma unroll
      for (int r = 0; r < 4; r++){
        int rowg = rbase + r;
        int b = rowg >> 11, s = rowg & 2047;
        u16 v = f2bf((acc[m][n][r] + bb) * qscale);
        if (sel == 0)      Qb [(((size_t)(b*16 + h))*SEQ + s)*HDIM + d] = v;
        else if (sel == 1) Kb [(((size_t)(b*16 + h))*SEQ + s)*HDIM + d] = v;
        else               Vtb[(((size_t)(b*16 + h))*HDIM + d)*SEQ + s] = v;
      }
    }
  }
}

// ---------------- flash attention ----------------
// swapped QK^T (lane holds one q-column), exp2-domain online softmax, defer-max,
// P->A-frag via cvt_pk + permlane swaps (no LDS round-trip),
// double-buffered K/V staging with single raw barrier per tile.
__global__ __launch_bounds__(256) void attn_kernel(
    const u16* __restrict__ Qb, const u16* __restrict__ Kb, const u16* __restrict__ Vtb,
    u16* __restrict__ AOb)
{
  __shared__ __attribute__((aligned(16))) u16 Ks[2][64*64];  // [kv][d] swizzled
  __shared__ __attribute__((aligned(16))) u16 Vs[2][64*64];  // [d][kv] swizzled
  const int tid = threadIdx.x, wave = tid >> 6, lane = tid & 63;
  const int lr = lane & 15, lg = lane >> 4;
  const int bh = blockIdx.y;
  const int q0 = blockIdx.x * 128;
  const u16* Qh = Qb  + (size_t)bh * SEQ * HDIM;
  const u16* Kh = Kb  + (size_t)bh * SEQ * HDIM;
  const u16* Vh = Vtb + (size_t)bh * HDIM * SEQ;

#define STAGE_KV(kv0, buf) do { \
  _Pragma("unroll") \
  for (int i_ = 0; i_ < 2; i_++){ \
    int u_ = i_*256 + tid; \
    int r_ = u_ >> 3, s_ = u_ & 7, ss_ = s_ ^ (r_ & 7); \
    gload16(Kh + (size_t)((kv0) + r_) * HDIM + ss_*8, &Ks[buf][u_*8]); \
    gload16(Vh + (size_t)r_ * SEQ + (kv0) + ss_*8,    &Vs[buf][u_*8]); \
  } } while(0)

  // Q B-frags (col=q=lr, k=d): qf[qb][ks]
  bf16x8 qf[2][2];
#pragma unroll
  for (int qb = 0; qb < 2; qb++)
#pragma unroll
    for (int ks = 0; ks < 2; ks++)
      qf[qb][ks] = *(const bf16x8*)&Qh[(size_t)(q0 + wave*32 + qb*16 + lr) * HDIM + ks*32 + lg*8];

  f32x4 zero = {0.f, 0.f, 0.f, 0.f};
  f32x4 acc[2][4];
#pragma unroll
  for (int qb = 0; qb < 2; qb++)
#pragma unroll
    for (int fd = 0; fd < 4; fd++) acc[qb][fd] = zero;
  float m_c[2] = {-1e30f, -1e30f};
  float l_c[2] = {0.f, 0.f};   // per-lane partial sums; cross-lane reduced once at end

  STAGE_KV(0, 0);
  for (int t = 0; t < 32; t++){
    int cur = t & 1;
    asm volatile("s_waitcnt vmcnt(0)" ::: "memory");
    __builtin_amdgcn_s_barrier();
    __builtin_amdgcn_sched_barrier(0);
    if (t < 31) STAGE_KV((t+1)*64, cur ^ 1);
    const u16* Kc = &Ks[cur][0];
    const u16* Vc = &Vs[cur][0];

    // S^T = K Q^T (log2 domain): col=lr=q, row=lg*4+r=kv within block f
    f32x4 st[2][4];
    __builtin_amdgcn_s_setprio(1);
#pragma unroll
    for (int f = 0; f < 4; f++){
      bf16x8 kf0 = *(const bf16x8*)&Kc[(f*16 + lr)*64 + ((lg     ^ (lr & 7)) * 8)];
      bf16x8 kf1 = *(const bf16x8*)&Kc[(f*16 + lr)*64 + (((4+lg) ^ (lr & 7)) * 8)];
      st[0][f] = MFMA16(kf0, qf[0][0], zero);
      st[0][f] = MFMA16(kf1, qf[0][1], st[0][f]);
      st[1][f] = MFMA16(kf0, qf[1][0], zero);
      st[1][f] = MFMA16(kf1, qf[1][1], st[1][f]);
    }
    __builtin_amdgcn_s_setprio(0);

    // in-lane max (binary tree; compiler fuses to v_max3)
    float pm0, pm1;
    {
      float a0 = fmaxf(fmaxf(st[0][0][0], st[0][0][1]), fmaxf(st[0][0][2], st[0][0][3]));
      float a1 = fmaxf(fmaxf(st[0][1][0], st[0][1][1]), fmaxf(st[0][1][2], st[0][1][3]));
      float a2 = fmaxf(fmaxf(st[0][2][0], st[0][2][1]), fmaxf(st[0][2][2], st[0][2][3]));
      float a3 = fmaxf(fmaxf(st[0][3][0], st[0][3][1]), fmaxf(st[0][3][2], st[0][3][3]));
      pm0 = fmaxf(fmaxf(a0, a1), fmaxf(a2, a3));
      float b0 = fmaxf(fmaxf(st[1][0][0], st[1][0][1]), fmaxf(st[1][0][2], st[1][0][3]));
      float b1 = fmaxf(fmaxf(st[1][1][0], st[1][1][1]), fmaxf(st[1][1][2], st[1][1][3]));
      float b2 = fmaxf(fmaxf(st[1][2][0], st[1][2][1]), fmaxf(st[1][2][2], st[1][2][3]));
      float b3 = fmaxf(fmaxf(st[1][3][0], st[1][3][1]), fmaxf(st[1][3][2], st[1][3][3]));
      pm1 = fmaxf(fmaxf(b0, b1), fmaxf(b2, b3));
    }
    // defer-max: steady state needs no cross-lane reduce, no rescale (THR=11.5 log2 units)
    int need = (pm0 > m_c[0] + 11.5f) || (pm1 > m_c[1] + 11.5f);
    if (__any(need)){
#pragma unroll
      for (int qb = 0; qb < 2; qb++){
        float mt = (qb == 0) ? pm0 : pm1;
        mt = fmaxf(mt, __shfl_xor(mt, 16));
        mt = fmaxf(mt, __shfl_xor(mt, 32));
        float mn = fmaxf(m_c[qb], mt);
        float al = __builtin_amdgcn_exp2f(m_c[qb] - mn);
        m_c[qb] = mn;
        l_c[qb] *= al;
        float a0 = __shfl(al, lg*4 + 0), a1 = __shfl(al, lg*4 + 1);
        float a2 = __shfl(al, lg*4 + 2), a3 = __shfl(al, lg*4 + 3);
#pragma unroll
        for (int fd = 0; fd < 4; fd++){
          acc[qb][fd][0] *= a0; acc[qb][fd][1] *= a1;
          acc[qb][fd][2] *= a2; acc[qb][fd][3] *= a3;
        }
      }
    }

    // P = exp2(S - m); pack to bf16 pairs; permlane-swap into PV A-frag layout.
    // a[ks][t] at group lg = w[2ks+(lg>>1)][t&1] from group 2(lg&1)+(t>>1)
    //   == permlane16_swap(permlane32_swap(X=w[2ks][rr], Y=w[2ks+1][rr]))
    bf16x8 pa[2][2];
#pragma unroll
    for (int qb = 0; qb < 2; qb++){
      unsigned w[4][2];
      float ssum = 0.f;
#pragma unroll
      for (int f = 0; f < 4; f++){
        float p0 = __builtin_amdgcn_exp2f(st[qb][f][0] - m_c[qb]);
        float p1 = __builtin_amdgcn_exp2f(st[qb][f][1] - m_c[qb]);
        float p2 = __builtin_amdgcn_exp2f(st[qb][f][2] - m_c[qb]);
        float p3 = __builtin_amdgcn_exp2f(st[qb][f][3] - m_c[qb]);
        ssum += (p0 + p1) + (p2 + p3);
        asm("v_cvt_pk_bf16_f32 %0, %1, %2" : "=v"(w[f][0]) : "v"(p0), "v"(p1));
        asm("v_cvt_pk_bf16_f32 %0, %1, %2" : "=v"(w[f][1]) : "v"(p2), "v"(p3));
      }
      l_c[qb] += ssum;
#pragma unroll
      for (int ks = 0; ks < 2; ks++){
        u32x4 aw;
#pragma unroll
        for (int rr = 0; rr < 2; rr++){
          unsigned X = w[2*ks][rr], Y = w[2*ks+1][rr];
          asm("v_permlane32_swap_b32 %0, %1" : "+v"(X), "+v"(Y));
          asm("v_permlane16_swap_b32 %0, %1" : "+v"(X), "+v"(Y));
          aw[rr] = X; aw[2 + rr] = Y;
        }
        pa[qb][ks] = __builtin_bit_cast(bf16x8, aw);
      }
    }

    // PV: A=P[q][kv] (reg frags), B=V^T[d][kv] -> acc[q][d]
    __builtin_amdgcn_s_setprio(1);
#pragma unroll
    for (int ks = 0; ks < 2; ks++)
#pragma unroll
      for (int fd = 0; fd < 4; fd++){
        bf16x8 vf = *(const bf16x8*)&Vc[(fd*16 + lr)*64 + (((ks*4 + lg) ^ (lr & 7)) * 8)];
        acc[0][fd] = MFMA16(pa[0][ks], vf, acc[0][fd]);
        acc[1][fd] = MFMA16(pa[1][ks], vf, acc[1][fd]);
      }
    __builtin_amdgcn_s_setprio(0);
  }

  // epilogue: reduce l across lane groups once; AOb[b][s][h*64+d] bf16
  const int b = bh >> 4, h = bh & 15;
#pragma unroll
  for (int qb = 0; qb < 2; qb++){
    float lt = l_c[qb];
    lt += __shfl_xor(lt, 16);
    lt += __shfl_xor(lt, 32);
    float li[4];
#pragma unroll
    for (int r = 0; r < 4; r++) li[r] = 1.0f / __shfl(lt, lg*4 + r);
#pragma unroll
    for (int fd = 0; fd < 4; fd++){
      int d = h*64 + fd*16 + lr;
#pragma unroll
      for (int r = 0; r < 4; r++){
        int s = q0 + wave*32 + qb*16 + lg*4 + r;
        AOb[((size_t)(b*SEQ + s))*HID + d] = f2bf(acc[qb][fd][r] * li[r]);
      }
    }
  }
}

// ---------------- output projection: Out = AO @ Wo^T + bo (fp32 out) ----------------
__global__ __launch_bounds__(256) void gemm_out(
    const u16* __restrict__ Ab, const u16* __restrict__ Wob,
    const float* __restrict__ bo, float* __restrict__ Out)
{
  __shared__ __attribute__((aligned(16))) u16 As[2][128*32];
  __shared__ __attribute__((aligned(16))) u16 Bs[2][128*32];
  const int tid = threadIdx.x, wave = tid >> 6, lane = tid & 63;
  const int m0 = blockIdx.x * 128, n0 = blockIdx.y * 128;
  const int wr = (wave >> 1) * 64, wc = (wave & 1) * 64;
  const int lr = lane & 15, lg = lane >> 4, kseg = lg * 8;

  f32x4 zero = {0.f, 0.f, 0.f, 0.f};
  f32x4 acc[4][4];
#pragma unroll
  for (int i = 0; i < 4; i++)
#pragma unroll
    for (int j = 0; j < 4; j++) acc[i][j] = zero;

  STAGE_G(Ab, Wob, 0, 0);
  for (int t = 0; t < 32; t++){
    int cur = t & 1;
    asm volatile("s_waitcnt vmcnt(0)" ::: "memory");
    __builtin_amdgcn_s_barrier();
    __builtin_amdgcn_sched_barrier(0);
    if (t < 31) STAGE_G(Ab, Wob, (t+1)*32, cur ^ 1);
    const u16* Ac = As[cur]; const u16* Bc = Bs[cur];
    bf16x8 af[4], bfr[4];
#pragma unroll
    for (int m = 0; m < 4; m++) af[m]  = *(const bf16x8*)&Ac[(wr + m*16 + lr)*32 + kseg];
#pragma unroll
    for (int n = 0; n < 4; n++) bfr[n] = *(const bf16x8*)&Bc[(wc + n*16 + lr)*32 + kseg];
    __builtin_amdgcn_s_setprio(1);
#pragma unroll
    for (int m = 0; m < 4; m++)
#pragma unroll
      for (int n = 0; n < 4; n++)
        acc[m][n] = MFMA16(af[m], bfr[n], acc[m][n]);
    __builtin_amdgcn_s_setprio(0);
  }

#pragma unroll
  for (int n = 0; n < 4; n++){
    int col = n0 + wc + n*16 + lr;
    float bb = bo[col];
#pragma unroll
    for (int m = 0; m < 4; m++){
      int rbase = m0 + wr + m*16 + lg*4;
#pragma unroll
      for (int r = 0; r < 4; r++)
        Out[(size_t)(rbase + r) * HID + col] = acc[m][n][r] + bb;
    }
  }
}

extern "C" void kernel_launch(void* const* d_in, const int* in_sizes, int n_in,
                              void* d_out, int out_size, void* d_ws, size_t ws_size,
                              hipStream_t stream){
  const float* hs = (const float*)d_in[0];
  const float* Wq = (const float*)d_in[1];
  const float* bq = (const float*)d_in[2];
  const float* Wk = (const float*)d_in[3];
  const float* bk = (const float*)d_in[4];
  const float* Wv = (const float*)d_in[5];
  const float* bv = (const float*)d_in[6];
  const float* Wo = (const float*)d_in[7];
  const float* bo = (const float*)d_in[8];
  float* Out = (float*)d_out;

  u16* Xb   = (u16*)d_ws;                          // 4096x1024
  u16* Wqkv = Xb   + (size_t)MTOK * HID;           // 3072x1024
  u16* Wob  = Wqkv + (size_t)3 * HID * HID;        // 1024x1024
  u16* Qb   = Wob  + (size_t)HID * HID;            // [b][h][s][d] (scaled, log2 domain)
  u16* Kb   = Qb   + (size_t)MTOK * HID;           // [b][h][s][d]
  u16* Vtb  = Kb   + (size_t)MTOK * HID;           // [b][h][d][s]
  u16* AOb  = Vtb  + (size_t)MTOK * HID;           // [b][s][h*d]

  cast_f32_bf16<<<2048, 256, 0, stream>>>(hs, Xb, MTOK * HID / 8);
  cast_w4<<<dim3(HID*HID/8/256, 4), 256, 0, stream>>>(Wq, Wk, Wv, Wo, Wqkv, Wob);

  gemm_qkv<<<dim3(MTOK/128, 3*HID/128), 256, 0, stream>>>(Xb, Wqkv, bq, bk, bv, Qb, Kb, Vtb);
  attn_kernel<<<dim3(SEQ/128, 2*NHEAD), 256, 0, stream>>>(Qb, Kb, Vtb, AOb);
  gemm_out<<<dim3(MTOK/128, HID/128), 256, 0, stream>>>(AOb, Wob, bo, Out);
}